// Round 1
// baseline (328.992 us; speedup 1.0000x reference)
//
#include <hip/hip_runtime.h>

#define BB 4
#define NTOK 2048
#define E 96
#define NH 6
#define DH 16
#define E3 288
#define GSZ (E*E)          // 9216
#define PART (GSZ + E)     // 9312 floats per partial block (G + s)
#define SCALE 0.25f        // D^-0.5 = 1/sqrt(16)

// ---------------- K1: partial G = X^T X and s = sum of rows, split over N ----
__global__ __launch_bounds__(256) void k_gpart(const float* __restrict__ x,
                                               float* __restrict__ gpart, int nsplit) {
    const int blk = blockIdx.x;
    const int b = blk / nsplit, sp = blk % nsplit;
    const int rows = NTOK / nsplit;
    const int n0 = sp * rows;
    __shared__ float4 xs4[64 * 25];          // 64 rows x 100-float stride
    float* xs = (float*)xs4;
    const int t = threadIdx.x;
    const int te1 = (t >> 4) * 6, te2 = (t & 15) * 6;   // 16x16 tiles of 6x6
    float acc[36];
#pragma unroll
    for (int i = 0; i < 36; i++) acc[i] = 0.f;
    float sacc = 0.f;

    for (int ch = 0; ch < rows; ch += 64) {
        __syncthreads();
        const float4* x4 = (const float4*)(x + ((size_t)b * NTOK + n0 + ch) * E);
#pragma unroll
        for (int i = 0; i < 6; i++) {         // 64*24 = 1536 float4
            int f = t + i * 256;
            xs4[(f / 24) * 25 + (f % 24)] = x4[f];
        }
        __syncthreads();
        for (int n = 0; n < 64; n++) {
            float a[6], c[6];
#pragma unroll
            for (int j = 0; j < 6; j++) { a[j] = xs[n * 100 + te1 + j]; c[j] = xs[n * 100 + te2 + j]; }
#pragma unroll
            for (int ii = 0; ii < 6; ii++)
#pragma unroll
                for (int jj = 0; jj < 6; jj++)
                    acc[ii * 6 + jj] += a[ii] * c[jj];
        }
        if (t < E) {
            for (int n = 0; n < 64; n++) sacc += xs[n * 100 + t];
        }
    }
    float* gp = gpart + (size_t)blk * PART;
#pragma unroll
    for (int ii = 0; ii < 6; ii++)
#pragma unroll
        for (int jj = 0; jj < 6; jj++)
            gp[(te1 + ii) * E + te2 + jj] = acc[ii * 6 + jj];
    if (t < E) gp[GSZ + t] = sacc;
}

// ---------------- K2: per-batch: reduce G,s -> M[h] -> T1 = Wq*BD(scale*M) ----
__global__ __launch_bounds__(256) void k_fold1(const float* __restrict__ Wqkv,
                                               const float* __restrict__ bqkv,
                                               const float* __restrict__ gpart,
                                               float* __restrict__ T1, int nsplit) {
    const int b = blockIdx.x;
    const int t = threadIdx.x;
    __shared__ float Gs[E * 100];
    __shared__ float Ps[E * 100];
    __shared__ float Ms[NH * DH * DH];   // 1536
    __shared__ float ss[E], sk[E], sv[E];

    // 1. reduce partials
    for (int i = 0; i < 37; i++) {
        int oidx = t + i * 256;
        if (oidx < PART) {
            float v = 0.f;
            const float* gp = gpart + (size_t)b * nsplit * PART + oidx;
            for (int sp = 0; sp < nsplit; sp++) v += gp[(size_t)sp * PART];
            if (oidx < GSZ) Gs[(oidx / E) * 100 + (oidx % E)] = v;
            else ss[oidx - GSZ] = v;
        }
    }
    __syncthreads();
    // 2. sk = s @ Wk, sv = s @ Wv
    if (t < 2 * E) {
        int j = (t < E) ? t : (t - E);
        int colbase = (t < E) ? (E + j) : (2 * E + j);
        float v = 0.f;
        for (int e = 0; e < E; e++) v += ss[e] * Wqkv[e * E3 + colbase];
        if (t < E) sk[j] = v; else sv[j] = v;
    }
    // 3. P = G @ Wv   (6x6 register tiles)
    const int te1 = (t >> 4) * 6, tj2 = (t & 15) * 6;
    float acc[36];
#pragma unroll
    for (int i = 0; i < 36; i++) acc[i] = 0.f;
    for (int e2 = 0; e2 < E; e2++) {
        float g[6], w[6];
#pragma unroll
        for (int ii = 0; ii < 6; ii++) g[ii] = Gs[(te1 + ii) * 100 + e2];
#pragma unroll
        for (int jj = 0; jj < 6; jj++) w[jj] = Wqkv[e2 * E3 + 2 * E + tj2 + jj];
#pragma unroll
        for (int ii = 0; ii < 6; ii++)
#pragma unroll
            for (int jj = 0; jj < 6; jj++)
                acc[ii * 6 + jj] += g[ii] * w[jj];
    }
#pragma unroll
    for (int ii = 0; ii < 6; ii++)
#pragma unroll
        for (int jj = 0; jj < 6; jj++)
            Ps[(te1 + ii) * 100 + tj2 + jj] = acc[ii * 6 + jj];
    __syncthreads();
    // 4. M[h][d1][d2] = scale * (Wk^T P + bias terms)
    for (int i = 0; i < 6; i++) {
        int oidx = t + i * 256;              // < 1536
        int h = oidx >> 8, rem = oidx & 255, d1 = rem >> 4, d2 = rem & 15;
        int j1 = h * DH + d1, j2 = h * DH + d2;
        float v = 0.f;
        for (int e1 = 0; e1 < E; e1++) v += Wqkv[e1 * E3 + E + j1] * Ps[e1 * 100 + j2];
        float bk = bqkv[E + j1], bv = bqkv[2 * E + j2];
        v += bk * sv[j2] + sk[j1] * bv + (float)NTOK * bk * bv;
        Ms[oidx] = SCALE * v;
    }
    __syncthreads();
    // 5. T1[e][j2] = sum_d1 Wq[e][h*16+d1] * Ms[h][d1][d2];  row 96 = bias path
    float* T1b = T1 + (size_t)b * PART;
    for (int i = 0; i < 37; i++) {
        int oidx = t + i * 256;
        if (oidx < PART) {
            float v = 0.f;
            if (oidx < GSZ) {
                int e = oidx / E, j2 = oidx % E;
                int h = j2 >> 4, d2 = j2 & 15;
                for (int d1 = 0; d1 < DH; d1++)
                    v += Wqkv[e * E3 + h * DH + d1] * Ms[(h * DH + d1) * DH + d2];
            } else {
                int j2 = oidx - GSZ; int h = j2 >> 4, d2 = j2 & 15;
                for (int d1 = 0; d1 < DH; d1++)
                    v += bqkv[h * DH + d1] * Ms[(h * DH + d1) * DH + d2];
            }
            T1b[oidx] = v;
        }
    }
}

// ---------------- K3: W_comb = T1 @ Wff (row 96: b_comb = t1b@Wff + bff) -----
__global__ __launch_bounds__(256) void k_fold2(const float* __restrict__ Wff,
                                               const float* __restrict__ bff,
                                               const float* __restrict__ T1,
                                               float* __restrict__ Wc) {
    const int blk = blockIdx.x;
    const int b = blk / 37, part = blk % 37;
    const int oidx = part * 256 + threadIdx.x;
    if (oidx >= PART) return;
    const int e = oidx / E, eo = oidx % E;
    const float* T1row = T1 + (size_t)b * PART + e * E;
    float v = (e == E) ? bff[eo] : 0.f;
    for (int j = 0; j < E; j++) v += T1row[j] * Wff[j * E + eo];
    Wc[(size_t)b * PART + oidx] = v;
}

// ---------------- K4: out[b] = x[b] @ Wc[b] + bc[b] --------------------------
__global__ __launch_bounds__(256) void k_out(const float* __restrict__ x,
                                             const float* __restrict__ Wc,
                                             float* __restrict__ out) {
    const int blk = blockIdx.x;              // BB * 64
    const int b = blk >> 6, tile = blk & 63;
    const int n0 = tile * 32;
    __shared__ float4 xs4[32 * 25];          // 32 rows x 100-float stride
    __shared__ float4 wcs4[97 * 25];         // 97 rows x 100-float stride
    float* xs = (float*)xs4;
    float* wcs = (float*)wcs4;
    const int t = threadIdx.x;

    const float4* x4 = (const float4*)(x + ((size_t)b * NTOK + n0) * E);
#pragma unroll
    for (int i = 0; i < 3; i++) {            // 32*24 = 768 float4
        int f = t + i * 256;
        xs4[(f / 24) * 25 + (f % 24)] = x4[f];
    }
    const float4* w4 = (const float4*)(Wc + (size_t)b * PART);
#pragma unroll
    for (int i = 0; i < 10; i++) {           // 2328 float4
        int f = t + i * 256;
        if (f < 2328) wcs4[(f / 24) * 25 + (f % 24)] = w4[f];
    }
    __syncthreads();

    const int r = t >> 3;                    // 0..31
    const int c4 = (t & 7) * 3;              // float4 col base (cols c4*4..c4*4+11)
    float acc[12];
#pragma unroll
    for (int j = 0; j < 12; j++) acc[j] = wcs[96 * 100 + c4 * 4 + j];   // bias row
    for (int k = 0; k < E; k++) {
        float xr = xs[r * 100 + k];
        float4 w0 = wcs4[k * 25 + c4];
        float4 w1 = wcs4[k * 25 + c4 + 1];
        float4 w2 = wcs4[k * 25 + c4 + 2];
        acc[0] += xr * w0.x; acc[1] += xr * w0.y; acc[2]  += xr * w0.z; acc[3]  += xr * w0.w;
        acc[4] += xr * w1.x; acc[5] += xr * w1.y; acc[6]  += xr * w1.z; acc[7]  += xr * w1.w;
        acc[8] += xr * w2.x; acc[9] += xr * w2.y; acc[10] += xr * w2.z; acc[11] += xr * w2.w;
    }
    float4* o4 = (float4*)(out + ((size_t)(b * NTOK + n0 + r)) * E + c4 * 4);
    o4[0] = make_float4(acc[0], acc[1], acc[2], acc[3]);
    o4[1] = make_float4(acc[4], acc[5], acc[6], acc[7]);
    o4[2] = make_float4(acc[8], acc[9], acc[10], acc[11]);
}

extern "C" void kernel_launch(void* const* d_in, const int* in_sizes, int n_in,
                              void* d_out, int out_size, void* d_ws, size_t ws_size,
                              hipStream_t stream) {
    const float* x    = (const float*)d_in[0];
    const float* Wqkv = (const float*)d_in[1];
    const float* bqkv = (const float*)d_in[2];
    const float* Wff  = (const float*)d_in[3];
    const float* bff  = (const float*)d_in[4];
    float* out = (float*)d_out;
    float* ws  = (float*)d_ws;

    int nsplit = 32;
    while (nsplit > 1 &&
           ((size_t)BB * nsplit * PART + 2ull * BB * PART) * sizeof(float) > ws_size)
        nsplit >>= 1;

    float* gpart = ws;
    float* T1 = ws + (size_t)BB * nsplit * PART;
    float* Wc = T1 + (size_t)BB * PART;

    k_gpart<<<BB * nsplit, 256, 0, stream>>>(x, gpart, nsplit);
    k_fold1<<<BB, 256, 0, stream>>>(Wqkv, bqkv, gpart, T1, nsplit);
    k_fold2<<<BB * 37, 256, 0, stream>>>(Wff, bff, T1, Wc);
    k_out<<<BB * 64, 256, 0, stream>>>(x, Wc, out);
}

// Round 2
// 48.068 us; speedup vs baseline: 6.8443x; 6.8443x over previous
//
#include <hip/hip_runtime.h>

#define BB 4
#define NTOK 2048
#define E 96
#define NH 6
#define DH 16
#define E3 288
#define GSZ (E*E)          // 9216
#define PART (GSZ + E)     // 9312 floats per partial block (G + s)
#define NSPLIT 32
#define SCALE 0.25f        // D^-0.5 = 1/sqrt(16)

// ---------------- K1: partial G = X^T X and s = row-sum, split over N --------
__global__ __launch_bounds__(256) void k_gpart(const float* __restrict__ x,
                                               float* __restrict__ gpart) {
    const int blk = blockIdx.x;              // b*NSPLIT + sp
    const int b = blk / NSPLIT, sp = blk % NSPLIT;
    const int n0 = sp * (NTOK / NSPLIT);     // 64 rows per block
    __shared__ float4 xs4[64 * 25];          // 64 rows x 100-float stride
    float* xs = (float*)xs4;
    const int t = threadIdx.x;
    const int te1 = (t >> 4) * 6, te2 = (t & 15) * 6;

    const float4* x4 = (const float4*)(x + ((size_t)b * NTOK + n0) * E);
#pragma unroll
    for (int i = 0; i < 6; i++) {            // 64*24 = 1536 float4
        int f = t + i * 256;
        xs4[(f / 24) * 25 + (f % 24)] = x4[f];
    }
    __syncthreads();

    float acc[36];
#pragma unroll
    for (int i = 0; i < 36; i++) acc[i] = 0.f;
    for (int n = 0; n < 64; n++) {
        float a[6], c[6];
#pragma unroll
        for (int j = 0; j < 6; j++) { a[j] = xs[n * 100 + te1 + j]; c[j] = xs[n * 100 + te2 + j]; }
#pragma unroll
        for (int ii = 0; ii < 6; ii++)
#pragma unroll
            for (int jj = 0; jj < 6; jj++)
                acc[ii * 6 + jj] += a[ii] * c[jj];
    }
    float* gp = gpart + (size_t)blk * PART;
#pragma unroll
    for (int ii = 0; ii < 6; ii++)
#pragma unroll
        for (int jj = 0; jj < 6; jj++)
            gp[(te1 + ii) * E + te2 + jj] = acc[ii * 6 + jj];
    if (t < E) {
        float sacc = 0.f;
        for (int n = 0; n < 64; n++) sacc += xs[n * 100 + t];
        gp[GSZ + t] = sacc;
    }
}

// ---------------- F1: per (b, 16-row group): reduce G rows, P = Grows @ Wv ---
__global__ __launch_bounds__(256) void k_redP(const float* __restrict__ Wqkv,
                                              const float* __restrict__ gpart,
                                              float* __restrict__ P) {
    const int b = blockIdx.x / 6, rg = blockIdx.x % 6;
    const int r0 = rg * 16;
    const int t = threadIdx.x;
    __shared__ float4 G4[16 * 24];           // 16 rows x 96 floats
    float* Gs = (float*)G4;

    const float4* gp4 = (const float4*)(gpart + (size_t)b * NSPLIT * PART) + r0 * 24;
    for (int f = t; f < 384; f += 256) {
        float4 a = make_float4(0.f, 0.f, 0.f, 0.f);
        const float4* p = gp4 + f;
#pragma unroll
        for (int sp = 0; sp < NSPLIT; sp++) {   // 32 independent loads in flight
            float4 g = p[(size_t)sp * (PART / 4)];
            a.x += g.x; a.y += g.y; a.z += g.z; a.w += g.w;
        }
        G4[f] = a;
    }
    __syncthreads();

    const int i = t >> 4, jb = (t & 15) * 6;
    float acc[6] = {0.f, 0.f, 0.f, 0.f, 0.f, 0.f};
    for (int e = 0; e < E; e++) {
        float g = Gs[i * 96 + e];
        const float* w = &Wqkv[e * E3 + 2 * E + jb];
#pragma unroll
        for (int j = 0; j < 6; j++) acc[j] += g * w[j];
    }
    float* Pr = P + ((size_t)b * E + (r0 + i)) * E + jb;
#pragma unroll
    for (int j = 0; j < 6; j++) Pr[j] = acc[j];
}

// ---------------- F2: per (b,h): M_h -> U rows + bias-row partial ------------
__global__ __launch_bounds__(256) void k_MU(const float* __restrict__ Wqkv,
                                            const float* __restrict__ bqkv,
                                            const float* __restrict__ Wff,
                                            const float* __restrict__ bff,
                                            const float* __restrict__ gpart,
                                            const float* __restrict__ P,
                                            float* __restrict__ U,
                                            float* __restrict__ u_part) {
    const int b = blockIdx.x / NH, h = blockIdx.x % NH;
    const int t = threadIdx.x;
    __shared__ float Ph[E * DH];             // 96 x 16
    __shared__ float ss[E], skk[DH], svv[DH], Ms[DH * DH], rr[DH];

    // stage P head columns (float4, 64B-aligned base)
    const float4* P4 = (const float4*)(P + (size_t)b * GSZ + h * DH);
    float4* Ph4 = (float4*)Ph;
    for (int f = t; f < 384; f += 256) {
        int e = f >> 2, q = f & 3;
        Ph4[e * 4 + q] = P4[e * 24 + q];
    }
    // reduce s (unrolled 32 -> pipelined loads)
    if (t < E) {
        float v = 0.f;
        const float* gp = gpart + (size_t)b * NSPLIT * PART + GSZ + t;
#pragma unroll
        for (int sp = 0; sp < NSPLIT; sp++) v += gp[(size_t)sp * PART];
        ss[t] = v;
    }
    __syncthreads();
    // sk, sv for this head
    if (t < 2 * DH) {
        int d = t & 15;
        int col = (t < DH) ? (E + h * DH + d) : (2 * E + h * DH + d);
        float v = 0.f;
        for (int e = 0; e < E; e++) v += ss[e] * Wqkv[e * E3 + col];
        if (t < DH) skk[d] = v; else svv[d] = v;
    }
    __syncthreads();
    // M_h[d1][d2]
    {
        const int d1 = t >> 4, d2 = t & 15;
        const int j1 = h * DH + d1;
        float v = 0.f;
        for (int e = 0; e < E; e++) v += Wqkv[e * E3 + E + j1] * Ph[e * DH + d2];
        float bk = bqkv[E + j1], bv = bqkv[2 * E + h * DH + d2];
        v += bk * svv[d2] + skk[d1] * bv + (float)NTOK * bk * bv;
        Ms[t] = SCALE * v;
    }
    __syncthreads();
    if (t < DH) {
        float v = 0.f;
#pragma unroll
        for (int d1 = 0; d1 < DH; d1++) v += bqkv[h * DH + d1] * Ms[d1 * DH + t];
        rr[t] = v;
    }
    __syncthreads();
    // U rows for this head
    {
        const int d1 = t >> 4, eb = (t & 15) * 6;
        float acc[6] = {0.f, 0.f, 0.f, 0.f, 0.f, 0.f};
#pragma unroll
        for (int d2 = 0; d2 < DH; d2++) {
            float m = Ms[d1 * DH + d2];
            const float* w = &Wff[(h * DH + d2) * E + eb];
#pragma unroll
            for (int j = 0; j < 6; j++) acc[j] += m * w[j];
        }
        float* Ur = U + ((size_t)b * E + h * DH + d1) * E + eb;
#pragma unroll
        for (int j = 0; j < 6; j++) Ur[j] = acc[j];
    }
    if (t < E) {
        float v = (h == 0) ? bff[t] : 0.f;
#pragma unroll
        for (int d2 = 0; d2 < DH; d2++) v += rr[d2] * Wff[(h * DH + d2) * E + t];
        u_part[((size_t)b * NH + h) * E + t] = v;
    }
}

// ---------------- F3: Wc = [Wq; bq-path] @ U  (row 96 = sum of u_part) -------
__global__ __launch_bounds__(256) void k_Wc(const float* __restrict__ Wqkv,
                                            const float* __restrict__ U,
                                            const float* __restrict__ u_part,
                                            float* __restrict__ Wc) {
    const int b = blockIdx.x / 7, part = blockIdx.x % 7;
    const int r0 = part * 14;
    const int t = threadIdx.x;
    __shared__ float4 Us4[GSZ / 4];          // 96x96 = 36 KB
    float* Us = (float*)Us4;
    const float4* U4 = (const float4*)(U + (size_t)b * GSZ);
    for (int f = t; f < GSZ / 4; f += 256) Us4[f] = U4[f];
    __syncthreads();

    const int row = t >> 4, cb = (t & 15) * 6;
    const int grow = r0 + row;
    if (row < 14 && grow < 97) {
        float acc[6] = {0.f, 0.f, 0.f, 0.f, 0.f, 0.f};
        if (grow == 96) {
#pragma unroll
            for (int h = 0; h < NH; h++) {
                const float* up = u_part + ((size_t)b * NH + h) * E + cb;
#pragma unroll
                for (int j = 0; j < 6; j++) acc[j] += up[j];
            }
        } else {
            for (int j1 = 0; j1 < E; j1++) {
                float wq = Wqkv[grow * E3 + j1];
                const float* u = &Us[j1 * E + cb];
#pragma unroll
                for (int j = 0; j < 6; j++) acc[j] += wq * u[j];
            }
        }
        float* o = Wc + (size_t)b * PART + grow * E + cb;
#pragma unroll
        for (int j = 0; j < 6; j++) o[j] = acc[j];
    }
}

// ---------------- K4: out[b] = x[b] @ Wc[b] + bias row -----------------------
__global__ __launch_bounds__(256) void k_out(const float* __restrict__ x,
                                             const float* __restrict__ Wc,
                                             float* __restrict__ out) {
    const int blk = blockIdx.x;              // BB * 64
    const int b = blk >> 6, tile = blk & 63;
    const int n0 = tile * 32;
    __shared__ float4 xs4[32 * 25];
    __shared__ float4 wcs4[97 * 25];
    float* xs = (float*)xs4;
    float* wcs = (float*)wcs4;
    const int t = threadIdx.x;

    const float4* x4 = (const float4*)(x + ((size_t)b * NTOK + n0) * E);
#pragma unroll
    for (int i = 0; i < 3; i++) {
        int f = t + i * 256;
        xs4[(f / 24) * 25 + (f % 24)] = x4[f];
    }
    const float4* w4 = (const float4*)(Wc + (size_t)b * PART);
#pragma unroll
    for (int i = 0; i < 10; i++) {
        int f = t + i * 256;
        if (f < 2328) wcs4[(f / 24) * 25 + (f % 24)] = w4[f];
    }
    __syncthreads();

    const int r = t >> 3;
    const int c4 = (t & 7) * 3;
    float acc[12];
#pragma unroll
    for (int j = 0; j < 12; j++) acc[j] = wcs[96 * 100 + c4 * 4 + j];
    for (int k = 0; k < E; k++) {
        float xr = xs[r * 100 + k];
        float4 w0 = wcs4[k * 25 + c4];
        float4 w1 = wcs4[k * 25 + c4 + 1];
        float4 w2 = wcs4[k * 25 + c4 + 2];
        acc[0] += xr * w0.x; acc[1] += xr * w0.y; acc[2]  += xr * w0.z; acc[3]  += xr * w0.w;
        acc[4] += xr * w1.x; acc[5] += xr * w1.y; acc[6]  += xr * w1.z; acc[7]  += xr * w1.w;
        acc[8] += xr * w2.x; acc[9] += xr * w2.y; acc[10] += xr * w2.z; acc[11] += xr * w2.w;
    }
    float4* o4 = (float4*)(out + ((size_t)(b * NTOK + n0 + r)) * E + c4 * 4);
    o4[0] = make_float4(acc[0], acc[1], acc[2], acc[3]);
    o4[1] = make_float4(acc[4], acc[5], acc[6], acc[7]);
    o4[2] = make_float4(acc[8], acc[9], acc[10], acc[11]);
}

extern "C" void kernel_launch(void* const* d_in, const int* in_sizes, int n_in,
                              void* d_out, int out_size, void* d_ws, size_t ws_size,
                              hipStream_t stream) {
    const float* x    = (const float*)d_in[0];
    const float* Wqkv = (const float*)d_in[1];
    const float* bqkv = (const float*)d_in[2];
    const float* Wff  = (const float*)d_in[3];
    const float* bff  = (const float*)d_in[4];
    float* out = (float*)d_out;
    float* ws  = (float*)d_ws;

    float* gpart  = ws;                                   // BB*NSPLIT*PART
    float* P      = ws + (size_t)BB * NSPLIT * PART;      // BB*GSZ
    float* U      = P + (size_t)BB * GSZ;                 // BB*GSZ
    float* u_part = U + (size_t)BB * GSZ;                 // BB*NH*E
    float* Wc     = ws;                                   // aliases gpart (dead after k_MU)

    k_gpart<<<BB * NSPLIT, 256, 0, stream>>>(x, gpart);
    k_redP<<<BB * 6, 256, 0, stream>>>(Wqkv, gpart, P);
    k_MU<<<BB * NH, 256, 0, stream>>>(Wqkv, bqkv, Wff, bff, gpart, P, U, u_part);
    k_Wc<<<BB * 7, 256, 0, stream>>>(Wqkv, U, u_part, Wc);
    k_out<<<BB * 64, 256, 0, stream>>>(x, Wc, out);
}